// Round 1
// baseline (245.547 us; speedup 1.0000x reference)
//
#include <hip/hip_runtime.h>

// EMA recurrence: s_t = alpha*s_{t-1} + (1-alpha)*x_t
// x: (T=1024, 32, 1024) fp32, state: (32, 1024) fp32
// out = concat(all states (T,32,1024), final_state (32,1024))
//
// Strategy: channels (32*1024 = 32768) are independent; split time into
// chunks that start from zero state + 128-step warm-up (alpha^128 ~ 1.4e-6,
// far below the 7.8e-2 threshold). Gives 2048 waves (8/CU) instead of 512,
// at the cost of re-reading warm-up slices (mostly L3 hits; x is 128 MiB,
// L3 is 256 MiB).

constexpr int T = 1024;
constexpr int C = 32 * 1024;      // channels per timestep (contiguous)
constexpr int CHUNK = 256;        // timesteps per chunk
constexpr int NCHUNK = T / CHUNK; // 4
constexpr int WARM = 128;         // warm-up steps for chunks > 0

__global__ __launch_bounds__(256)
void ExponentialDecay_23708219474744_kernel(const float* __restrict__ x,
                                            const float* __restrict__ state,
                                            float* __restrict__ out) {
    const int ch = blockIdx.x * blockDim.x + threadIdx.x;   // 0..C-1, coalesced
    const int chunk = blockIdx.y;
    const int t0 = chunk * CHUNK;

    const float a = 0.9f;
    const float oma = 0.1f;

    float s;
    if (chunk == 0) {
        s = state[ch];
    } else {
        s = 0.0f;
        const int tw = t0 - WARM;
        #pragma unroll 8
        for (int t = tw; t < t0; ++t) {
            float xv = x[(size_t)t * C + ch];
            s = fmaf(s, a, xv * oma);
        }
    }

    const int t1 = t0 + CHUNK;
    #pragma unroll 8
    for (int t = t0; t < t1; ++t) {
        float xv = x[(size_t)t * C + ch];
        s = fmaf(s, a, xv * oma);
        out[(size_t)t * C + ch] = s;
    }

    if (chunk == NCHUNK - 1) {
        // final_state, appended after the (T,32,1024) outputs
        out[(size_t)T * C + ch] = s;
    }
}

extern "C" void kernel_launch(void* const* d_in, const int* in_sizes, int n_in,
                              void* d_out, int out_size, void* d_ws, size_t ws_size,
                              hipStream_t stream) {
    const float* x = (const float*)d_in[0];
    const float* state = (const float*)d_in[1];
    float* out = (float*)d_out;

    dim3 block(256);
    dim3 grid(C / 256, NCHUNK);
    ExponentialDecay_23708219474744_kernel<<<grid, block, 0, stream>>>(x, state, out);
}